// Round 16
// baseline (343.338 us; speedup 1.0000x reference)
//
#include <hip/hip_runtime.h>
#include <hip/hip_bf16.h>

typedef float v4 __attribute__((ext_vector_type(4)));
typedef float f32x4 __attribute__((ext_vector_type(4)));
typedef short bf16x8 __attribute__((ext_vector_type(8)));
typedef unsigned short us8 __attribute__((ext_vector_type(8)));
typedef unsigned short us4 __attribute__((ext_vector_type(4)));

__device__ __forceinline__ unsigned short f2bf(float f) {
    unsigned u = __float_as_uint(f);
    u = (u + 0x7FFFu + ((u >> 16) & 1u)) >> 16;
    return (unsigned short)u;
}
__device__ __forceinline__ float bf2f(unsigned short s) {
    return __uint_as_float(((unsigned)s) << 16);
}
__device__ __forceinline__ float bf2f_lo(unsigned u) { return __uint_as_float(u << 16); }
__device__ __forceinline__ float bf2f_hi(unsigned u) { return __uint_as_float(u & 0xffff0000u); }

// ---------------- fused setup, partition order: [pack | bc | zero | hist | embed]
// embed: 8 channels/thread — x loaded once to regs, w read as float4 pairs.
// cnt+cursor must be zeroed by hipMemsetAsync BEFORE this kernel.
__global__ __launch_bounds__(256) void k_setup(
    const int* __restrict__ ei, int* __restrict__ cnt, int E_,
    const float* __restrict__ x, const float* __restrict__ embed_w,
    const float* __restrict__ embed_b, unsigned short* __restrict__ h_bf,
    const float* __restrict__ gat_lin_w,
    const float* __restrict__ vw, const float* __restrict__ vb,
    const float* __restrict__ ow, const float* __restrict__ ob,
    unsigned short* __restrict__ Bpack, float* __restrict__ bc,
    float* __restrict__ gzero,
    int n, int nbH) {
    int b = blockIdx.x, tid = threadIdx.x;
    if (b < 256) {
        // pack W[m] into MFMA B-fragment order; m==3 computes Wc = Vw@Ow on the fly
        int m = b >> 6;
        int idx = (b & 63) * 256 + tid;  // 0..16383
        int e = idx & 7, l = (idx >> 3) & 63, kb = (idx >> 9) & 3, c = idx >> 11;
        int k = kb * 32 + ((l >> 4) << 3) + e;
        int col = c * 16 + (l & 15);
        float val;
        if (m < 3) {
            val = gat_lin_w[(size_t)m * 16384 + k * 128 + col];
        } else {
            val = 0.f;
            for (int m2 = 0; m2 < 128; ++m2) val += vw[k * 128 + m2] * ow[m2 * 128 + col];
        }
        Bpack[(size_t)m * 16384 + idx] = f2bf(val);
    } else if (b == 256) {
        // bc = vb @ Ow + ob
        if (tid < 128) {
            float bv = ob[tid];
            for (int m2 = 0; m2 < 128; ++m2) bv += vb[m2] * ow[m2 * 128 + tid];
            bc[tid] = bv;
        }
    } else if (b < 257 + 64) {
        // zero gsum + gmax (2*G*128 floats = 16384)
        int idx = (b - 257) * 256 + tid;
        if (idx < 16384) gzero[idx] = 0.f;
    } else if (b < 257 + 64 + nbH) {
        // histogram of dst degrees (cnt pre-zeroed by memset)
        int e = (b - 257 - 64) * 256 + tid;
        if (e < E_) atomicAdd(&cnt[ei[E_ + e]], 1);
    } else {
        // embed: 8 channels/thread; h_bf = bf16(relu(x @ embed_w + embed_b))
        int idx = (b - 257 - 64 - nbH) * 256 + tid;  // over n*16
        if (idx >= n * 16) return;
        int node = idx >> 4;
        int j0 = (idx & 15) * 8;
        float xv[20];
#pragma unroll
        for (int k = 0; k < 20; ++k) xv[k] = x[node * 20 + k];
        v4 acc0 = *(const v4*)&embed_b[j0];
        v4 acc1 = *(const v4*)&embed_b[j0 + 4];
#pragma unroll
        for (int k = 0; k < 20; ++k) {
            v4 w0 = *(const v4*)&embed_w[k * 128 + j0];
            v4 w1 = *(const v4*)&embed_w[k * 128 + j0 + 4];
#pragma unroll
            for (int j = 0; j < 4; ++j) acc0[j] += xv[k] * w0[j];
#pragma unroll
            for (int j = 0; j < 4; ++j) acc1[j] += xv[k] * w1[j];
        }
        us8 o;
#pragma unroll
        for (int j = 0; j < 4; ++j) o[j] = f2bf(fmaxf(acc0[j], 0.f));
#pragma unroll
        for (int j = 0; j < 4; ++j) o[4 + j] = f2bf(fmaxf(acc1[j], 0.f));
        *(us8*)&h_bf[(size_t)node * 128 + j0] = o;
    }
}

// ---------------- CSR build (once; edge_index is layer-invariant) ----------------

__global__ __launch_bounds__(256) void k_scan_local(const int* __restrict__ cnt,
                                                    int* __restrict__ ptr,
                                                    int* __restrict__ bsum, int n) {
    __shared__ int s[256];
    int t = threadIdx.x, i = blockIdx.x * 256 + t;
    int v = (i < n) ? cnt[i] : 0;
    s[t] = v;
    __syncthreads();
    for (int o = 1; o < 256; o <<= 1) {
        int x = (t >= o) ? s[t - o] : 0;
        __syncthreads();
        s[t] += x;
        __syncthreads();
    }
    if (i < n) ptr[i] = s[t] - v;
    if (t == 255) bsum[blockIdx.x] = s[255];
}

// fused: each block computes its own exclusive bsum-prefix, then adds it.
__global__ __launch_bounds__(256) void k_scan_add2(int* __restrict__ ptr,
                                                   const int* __restrict__ bsum,
                                                   int n, int E_) {
    __shared__ int ws[4];
    __shared__ int soff;
    int t = threadIdx.x;
    int part = 0;
    for (int j = t; j < (int)blockIdx.x; j += 256) part += bsum[j];
#pragma unroll
    for (int o = 32; o; o >>= 1) part += __shfl_xor(part, o);
    if ((t & 63) == 0) ws[t >> 6] = part;
    __syncthreads();
    if (t == 0) soff = ws[0] + ws[1] + ws[2] + ws[3];
    __syncthreads();
    int i = blockIdx.x * 256 + t;
    if (i < n) ptr[i] += soff;
    if (i == 0) ptr[n] = E_;
}

// scatter into CSR slots; ONE 16B record per edge: {src, ea01, ea23, 0}
__global__ __launch_bounds__(256) void k_scatter(const int* __restrict__ ei,
                                                 const float* __restrict__ edge_attr,
                                                 const int* __restrict__ ptr,
                                                 int* __restrict__ cursor,
                                                 int4* __restrict__ erec, int E_) {
    int e = blockIdx.x * 256 + threadIdx.x;
    if (e >= E_) return;
    int d = ei[E_ + e];
    int p = ptr[d] + atomicAdd(&cursor[d], 1);
    v4 ea = ((const v4*)edge_attr)[e];
    int4 r;
    r.x = ei[e];
    r.y = (int)((unsigned)f2bf(ea[0]) | ((unsigned)f2bf(ea[1]) << 16));
    r.z = (int)((unsigned)f2bf(ea[2]) | ((unsigned)f2bf(ea[3]) << 16));
    r.w = 0;
    erec[p] = r;
}

// ---------------- MFMA GEMM [nn,128](bf16) x [128,128](packed bf16) ----------------
template <bool ALPHAS, bool OUTF32>
__global__ __launch_bounds__(256) void k_gemm_mfma(
    const unsigned short* __restrict__ A,     // [Npad][128] bf16
    const unsigned short* __restrict__ Bpack, // [32][64][8] bf16
    const float* __restrict__ bias,           // OUTF32
    unsigned short* __restrict__ out_bf,      // !OUTF32
    float* __restrict__ out_f32,              // OUTF32
    const float* __restrict__ avs, const float* __restrict__ avd,
    float* __restrict__ asrc, float* __restrict__ adst, int nn) {
    __shared__ float lds[64][132];
    int tid = threadIdx.x;
    int w = tid >> 6, l = tid & 63;
    int row0 = blockIdx.x * 64;
    int arow = row0 + w * 16 + (l & 15);
    int koff = (l >> 4) * 8;

    bf16x8 a[4];
#pragma unroll
    for (int kb = 0; kb < 4; ++kb)
        a[kb] = *(const bf16x8*)&A[(size_t)arow * 128 + kb * 32 + koff];

    const bf16x8* bp = (const bf16x8*)Bpack;
    f32x4 acc[8];
#pragma unroll
    for (int c = 0; c < 8; ++c) {
        f32x4 z = {0.f, 0.f, 0.f, 0.f};
        acc[c] = z;
#pragma unroll
        for (int kb = 0; kb < 4; ++kb)
            acc[c] = __builtin_amdgcn_mfma_f32_16x16x32_bf16(a[kb], bp[(c * 4 + kb) * 64 + l],
                                                             acc[c], 0, 0, 0);
    }

    int colb = l & 15;
    int rowb = w * 16 + (l >> 4) * 4;
#pragma unroll
    for (int c = 0; c < 8; ++c)
#pragma unroll
        for (int r = 0; r < 4; ++r)
            lds[rowb + r][c * 16 + colb] = acc[c][r];
    __syncthreads();

    int rl = tid >> 2, q = tid & 3;
    int gr = row0 + rl;
    if (gr >= nn) return;
    float v[32];
#pragma unroll
    for (int j = 0; j < 8; ++j)
        *(f32x4*)&v[j * 4] = *(const f32x4*)&lds[rl][q * 32 + j * 4];

    if (ALPHAS) {
        float ps = 0.f, pd = 0.f;
#pragma unroll
        for (int j = 0; j < 32; ++j) {
            ps += v[j] * avs[q * 32 + j];
            pd += v[j] * avd[q * 32 + j];
        }
        asrc[(size_t)gr * 4 + q] = ps;
        adst[(size_t)gr * 4 + q] = pd;
    }
    if (OUTF32) {
#pragma unroll
        for (int j = 0; j < 32; ++j) v[j] += bias[q * 32 + j];
#pragma unroll
        for (int j = 0; j < 8; ++j)
            *(f32x4*)&out_f32[(size_t)gr * 128 + q * 32 + j * 4] = *(f32x4*)&v[j * 4];
    } else {
        us8 o[4];
#pragma unroll
        for (int t = 0; t < 4; ++t)
#pragma unroll
            for (int j = 0; j < 8; ++j) o[t][j] = f2bf(v[t * 8 + j]);
#pragma unroll
        for (int t = 0; t < 4; ++t)
            *(us8*)&out_bf[(size_t)gr * 128 + q * 32 + t * 8] = o[t];
    }
}

// wave per node, 4 edge-groups x 16 lanes x 8 channels; merged 16B edge records;
// 2-way unrolled edge loop. LAST: also writes f32 h (model output).
template <bool LAST>
__global__ __launch_bounds__(256) void k_node_agg(
    const unsigned short* __restrict__ hl_bf, const int* __restrict__ ptr,
    const int4* __restrict__ erec,
    const float* __restrict__ asrc, const float* __restrict__ adst,
    const float* __restrict__ edge_w, const float* __restrict__ a_edge,
    const float* __restrict__ bias, const float* __restrict__ lng,
    const float* __restrict__ lnb, float* __restrict__ h_f32,
    unsigned short* __restrict__ h_bf, int n) {
    __shared__ float aew[16];  // [k*4 + head]
    int tid = threadIdx.x;
    if (tid < 16) {
        int k = tid >> 2, hh = tid & 3;
        float s = 0.f;
        for (int c = 0; c < 32; ++c) s += edge_w[k * 128 + hh * 32 + c] * a_edge[hh * 32 + c];
        aew[tid] = s;
    }
    __syncthreads();

    int node = blockIdx.x * 4 + (tid >> 6);
    if (node >= n) return;
    int lane = tid & 63;
    int g = lane >> 4;        // edge group 0..3
    int l16 = lane & 15;
    int c0 = l16 * 8;         // 8 channels per lane
    int hh = l16 >> 2;        // head of these channels

    float aewc0 = aew[hh], aewc1 = aew[4 + hh], aewc2 = aew[8 + hh], aewc3 = aew[12 + hh];
    int start = ptr[node], end = ptr[node + 1];
    float adn = adst[(size_t)node * 4 + hh];
    us8 res_bf = *(const us8*)&h_bf[(size_t)node * 128 + c0];  // residual, early issue

    const int4 zr = {0, 0, 0, 0};
    float acc[8] = {};
    float den = 0.f;
    int p = start + g;
    int4 r0 = (p < end) ? erec[p] : zr;
    int4 r1 = (p + 4 < end) ? erec[p + 4] : zr;
    for (; p < end; p += 8) {
        bool v1 = (p + 4 < end);
        int4 rn0 = (p + 8 < end) ? erec[p + 8] : zr;
        int4 rn1 = (p + 12 < end) ? erec[p + 12] : zr;
        int s0 = r0.x, s1 = r1.x;
        us8 hv0 = *(const us8*)&hl_bf[(size_t)s0 * 128 + c0];
        us8 hv1 = *(const us8*)&hl_bf[(size_t)s1 * 128 + c0];
        float as0 = asrc[(size_t)s0 * 4 + hh];
        float as1 = asrc[(size_t)s1 * 4 + hh];
        float a0 = as0 + adn + bf2f_lo((unsigned)r0.y) * aewc0 + bf2f_hi((unsigned)r0.y) * aewc1 +
                   bf2f_lo((unsigned)r0.z) * aewc2 + bf2f_hi((unsigned)r0.z) * aewc3;
        float a1 = as1 + adn + bf2f_lo((unsigned)r1.y) * aewc0 + bf2f_hi((unsigned)r1.y) * aewc1 +
                   bf2f_lo((unsigned)r1.z) * aewc2 + bf2f_hi((unsigned)r1.z) * aewc3;
        a0 = a0 > 0.f ? a0 : 0.2f * a0;
        a1 = a1 > 0.f ? a1 : 0.2f * a1;
        float ex0 = __expf(a0);
        float ex1 = v1 ? __expf(a1) : 0.f;
        den += ex0 + ex1;
#pragma unroll
        for (int j = 0; j < 8; ++j)
            acc[j] += ex0 * bf2f(hv0[j]) + ex1 * bf2f(hv1[j]);
        r0 = rn0; r1 = rn1;
    }

    // combine the 4 edge groups (lanes l16, l16+16, l16+32, l16+48 share channels)
#pragma unroll
    for (int j = 0; j < 8; ++j) {
        acc[j] += __shfl_xor(acc[j], 16);
        acc[j] += __shfl_xor(acc[j], 32);
    }
    den += __shfl_xor(den, 16);
    den += __shfl_xor(den, 32);

    float inv = 1.f / (den + 1e-16f);
    v4 b0 = *(const v4*)&bias[c0];
    v4 b1 = *(const v4*)&bias[c0 + 4];
    float v[8];
#pragma unroll
    for (int j = 0; j < 4; ++j) v[j] = acc[j] * inv + b0[j] + bf2f(res_bf[j]);
#pragma unroll
    for (int j = 0; j < 4; ++j) v[4 + j] = acc[4 + j] * inv + b1[j] + bf2f(res_bf[4 + j]);

    float s = 0.f, sq = 0.f;
#pragma unroll
    for (int j = 0; j < 8; ++j) { s += v[j]; sq += v[j] * v[j]; }
#pragma unroll
    for (int o = 1; o < 16; o <<= 1) { s += __shfl_xor(s, o); sq += __shfl_xor(sq, o); }
    float mu = s * (1.f / 128.f);
    float var = sq * (1.f / 128.f) - mu * mu;
    float rs = rsqrtf(var + 1e-5f);

    if (g == 0) {
        v4 g0 = *(const v4*)&lng[c0];
        v4 g1 = *(const v4*)&lng[c0 + 4];
        v4 lb0 = *(const v4*)&lnb[c0];
        v4 lb1 = *(const v4*)&lnb[c0 + 4];
        v4 o0, o1;
#pragma unroll
        for (int j = 0; j < 4; ++j) o0[j] = fmaxf((v[j] - mu) * rs * g0[j] + lb0[j], 0.f);
#pragma unroll
        for (int j = 0; j < 4; ++j) o1[j] = fmaxf((v[4 + j] - mu) * rs * g1[j] + lb1[j], 0.f);
        us8 ob;
#pragma unroll
        for (int j = 0; j < 4; ++j) ob[j] = f2bf(o0[j]);
#pragma unroll
        for (int j = 0; j < 4; ++j) ob[4 + j] = f2bf(o1[j]);
        *(us8*)&h_bf[(size_t)node * 128 + c0] = ob;
        if (LAST) {
            *(v4*)&h_f32[(size_t)node * 128 + c0] = o0;
            *(v4*)&h_f32[(size_t)node * 128 + c0 + 4] = o1;
        }
    }
}

__device__ __forceinline__ int lower_bound_i(const int* a, int n, int key) {
    int lo = 0, hi = n;
    while (lo < hi) {
        int mid = (lo + hi) >> 1;
        if (a[mid] < key) lo = mid + 1; else hi = mid;
    }
    return lo;
}

// ---------------- two-stage pooling (bf16 input) ----------------

__global__ __launch_bounds__(256) void k_pool_part(const unsigned short* __restrict__ h_bf,
                                                   const int* __restrict__ batch,
                                                   float* __restrict__ gsum,
                                                   float* __restrict__ gmax,
                                                   int n, int chunk) {
    int start = blockIdx.x * chunk;
    int end = min(start + chunk, n);
    if (start >= end) return;
    int c0 = (threadIdx.x & 63) * 2;
    int strm = threadIdx.x >> 6;
    float s0 = 0.f, s1 = 0.f, m0 = 0.f, m1 = 0.f;
    int curg = -1;
    for (int node = start + strm; node < end; node += 4) {
        int g = batch[node];
        if (g != curg) {
            if (curg >= 0) {
                atomicAdd(&gsum[curg * 128 + c0], s0);
                atomicAdd(&gsum[curg * 128 + c0 + 1], s1);
                atomicMax((int*)&gmax[curg * 128 + c0], __float_as_int(m0));
                atomicMax((int*)&gmax[curg * 128 + c0 + 1], __float_as_int(m1));
            }
            curg = g; s0 = s1 = 0.f; m0 = m1 = 0.f;
        }
        unsigned u = *(const unsigned*)&h_bf[(size_t)node * 128 + c0];
        float v0 = __uint_as_float(u << 16);
        float v1 = __uint_as_float(u & 0xffff0000u);
        s0 += v0; s1 += v1;
        m0 = fmaxf(m0, v0); m1 = fmaxf(m1, v1);
    }
    if (curg >= 0) {
        atomicAdd(&gsum[curg * 128 + c0], s0);
        atomicAdd(&gsum[curg * 128 + c0 + 1], s1);
        atomicMax((int*)&gmax[curg * 128 + c0], __float_as_int(m0));
        atomicMax((int*)&gmax[curg * 128 + c0 + 1], __float_as_int(m1));
    }
}

// ---------------- fused tail: graph_out (blocks 0..G-1) | MHA GEMM (rest) ----------------
__global__ __launch_bounds__(256) void k_tail(
    const float* __restrict__ gsum, const float* __restrict__ gmax,
    const int* __restrict__ batch, const float* __restrict__ hf,
    const float* __restrict__ had_w1, const float* __restrict__ had_b1,
    const float* __restrict__ had_w2, const float* __restrict__ had_b2,
    const float* __restrict__ int_w1, const float* __restrict__ int_b1,
    const float* __restrict__ int_w2, const float* __restrict__ int_b2,
    const float* __restrict__ int_w3, const float* __restrict__ int_b3,
    const float* __restrict__ aff_w1, const float* __restrict__ aff_b1,
    const float* __restrict__ aff_w2, const float* __restrict__ aff_b2,
    const float* __restrict__ aff_w3, const float* __restrict__ aff_b3,
    float* __restrict__ inter_out, float* __restrict__ aff_out,
    const unsigned short* __restrict__ A, const unsigned short* __restrict__ Bpack,
    const float* __restrict__ bias, float* __restrict__ out_f32,
    int G_, int nn, int n) {
    __shared__ float lds[64][132];
    int tid = threadIdx.x;
    if ((int)blockIdx.x < G_) {
        // ---- graph_out ----
        __shared__ float comb[384];
        __shared__ float h1[128];
        __shared__ float z1[2][128];
        __shared__ float z2[2][64];
        int g = blockIdx.x;
        if (tid < 128) {
            int start = lower_bound_i(batch, n, g);
            int end = lower_bound_i(batch, n, g + 1);
            float cntf = (float)(end - start);
            comb[tid] = gsum[g * 128 + tid] / cntf;
            comb[128 + tid] = gmax[g * 128 + tid];
            float acc = had_b1[tid];
#pragma unroll
            for (int k = 0; k < 12; ++k) acc += hf[g * 12 + k] * had_w1[k * 128 + tid];
            h1[tid] = fmaxf(acc, 0.f);
        }
        __syncthreads();
        if (tid < 128) {
            float a2 = had_b2[tid];
            for (int k = 0; k < 128; ++k) a2 += h1[k] * had_w2[k * 128 + tid];
            comb[256 + tid] = a2;
        }
        __syncthreads();
        int hsel = tid >> 7, j = tid & 127;
        const float* w1 = hsel ? aff_w1 : int_w1;
        const float* b1 = hsel ? aff_b1 : int_b1;
        const float* w2 = hsel ? aff_w2 : int_w2;
        const float* b2 = hsel ? aff_b2 : int_b2;
        const float* w3 = hsel ? aff_w3 : int_w3;
        const float* b3 = hsel ? aff_b3 : int_b3;
        float acc = b1[j];
        for (int k = 0; k < 384; ++k) acc += comb[k] * w1[k * 128 + j];
        z1[hsel][j] = fmaxf(acc, 0.f);
        __syncthreads();
        if (j < 64) {
            float a2 = b2[j];
            for (int k = 0; k < 128; ++k) a2 += z1[hsel][k] * w2[k * 64 + j];
            z2[hsel][j] = fmaxf(a2, 0.f);
        }
        __syncthreads();
        if (j == 0) {
            float a3 = b3[0];
            for (int k = 0; k < 64; ++k) a3 += z2[hsel][k] * w3[k];
            if (hsel) aff_out[g] = a3;
            else inter_out[g] = 1.f / (1.f + __expf(-a3));
        }
        return;
    }
    // ---- MHA GEMM (OUTF32 path) ----
    int w = tid >> 6, l = tid & 63;
    int row0 = ((int)blockIdx.x - G_) * 64;
    int arow = row0 + w * 16 + (l & 15);
    int koff = (l >> 4) * 8;

    bf16x8 a[4];
#pragma unroll
    for (int kb = 0; kb < 4; ++kb)
        a[kb] = *(const bf16x8*)&A[(size_t)arow * 128 + kb * 32 + koff];

    const bf16x8* bp = (const bf16x8*)Bpack;
    f32x4 acc[8];
#pragma unroll
    for (int c = 0; c < 8; ++c) {
        f32x4 z = {0.f, 0.f, 0.f, 0.f};
        acc[c] = z;
#pragma unroll
        for (int kb = 0; kb < 4; ++kb)
            acc[c] = __builtin_amdgcn_mfma_f32_16x16x32_bf16(a[kb], bp[(c * 4 + kb) * 64 + l],
                                                             acc[c], 0, 0, 0);
    }
    int colb = l & 15;
    int rowb = w * 16 + (l >> 4) * 4;
#pragma unroll
    for (int c = 0; c < 8; ++c)
#pragma unroll
        for (int r = 0; r < 4; ++r)
            lds[rowb + r][c * 16 + colb] = acc[c][r];
    __syncthreads();

    int rl = tid >> 2, q = tid & 3;
    int gr = row0 + rl;
    if (gr >= nn) return;
    float v[32];
#pragma unroll
    for (int j = 0; j < 8; ++j)
        *(f32x4*)&v[j * 4] = *(const f32x4*)&lds[rl][q * 32 + j * 4];
#pragma unroll
    for (int j = 0; j < 32; ++j) v[j] += bias[q * 32 + j];
#pragma unroll
    for (int j = 0; j < 8; ++j)
        *(f32x4*)&out_f32[(size_t)gr * 128 + q * 32 + j * 4] = *(f32x4*)&v[j * 4];
}

extern "C" void kernel_launch(void* const* d_in, const int* in_sizes, int n_in,
                              void* d_out, int out_size, void* d_ws, size_t ws_size,
                              hipStream_t stream) {
    const float* x = (const float*)d_in[0];
    const float* edge_attr = (const float*)d_in[1];
    const float* haddock = (const float*)d_in[2];
    const int* ei = (const int*)d_in[3];
    const int* batch = (const int*)d_in[4];
    const float* embed_w = (const float*)d_in[5];
    const float* embed_b = (const float*)d_in[6];
    const float* gat_lin_w = (const float*)d_in[7];
    const float* gat_att_src = (const float*)d_in[8];
    const float* gat_att_dst = (const float*)d_in[9];
    const float* gat_edge_w = (const float*)d_in[10];
    const float* gat_att_edge = (const float*)d_in[11];
    const float* gat_bias = (const float*)d_in[12];
    const float* ln_g = (const float*)d_in[13];
    const float* ln_b = (const float*)d_in[14];
    const float* had_w1 = (const float*)d_in[15];
    const float* had_b1 = (const float*)d_in[16];
    const float* had_w2 = (const float*)d_in[17];
    const float* had_b2 = (const float*)d_in[18];
    const float* int_w1 = (const float*)d_in[19];
    const float* int_b1 = (const float*)d_in[20];
    const float* int_w2 = (const float*)d_in[21];
    const float* int_b2 = (const float*)d_in[22];
    const float* int_w3 = (const float*)d_in[23];
    const float* int_b3 = (const float*)d_in[24];
    const float* aff_w1 = (const float*)d_in[25];
    const float* aff_b1 = (const float*)d_in[26];
    const float* aff_w2 = (const float*)d_in[27];
    const float* aff_b2 = (const float*)d_in[28];
    const float* aff_w3 = (const float*)d_in[29];
    const float* aff_b3 = (const float*)d_in[30];
    const float* mha_v_w = (const float*)d_in[31];
    const float* mha_v_b = (const float*)d_in[32];
    const float* mha_o_w = (const float*)d_in[33];
    const float* mha_o_b = (const float*)d_in[34];

    const int N_ = in_sizes[0] / 20;
    const int E_ = in_sizes[1] / 4;
    const int G_ = in_sizes[2] / 12;
    const int Npad = (N_ + 63) & ~63;

    float* out_f = (float*)d_out;
    float* inter_out = out_f;
    float* aff_out = out_f + G_;
    float* attn_out = out_f + 2 * G_;
    float* h_buf = attn_out + (size_t)N_ * 128;  // f32 h output (written by last layer)

    // workspace layout (16B-aligned sections)
    unsigned short* h_bf = (unsigned short*)d_ws;              // Npad*128
    unsigned short* hl_bf = h_bf + (size_t)Npad * 128;         // Npad*128
    unsigned short* Bpack = hl_bf + (size_t)Npad * 128;        // 4*16384
    int4* erec = (int4*)(Bpack + 4 * 16384);                   // E*16B
    float* bc = (float*)(erec + E_);                           // 128
    float* asrc = bc + 128;                                    // N*4
    float* adst = asrc + (size_t)N_ * 4;                       // N*4
    float* gsum = adst + (size_t)N_ * 4;                       // G*128
    float* gmax = gsum + (size_t)G_ * 128;                     // G*128 (adjacent to gsum!)
    int* cnt = (int*)(gmax + (size_t)G_ * 128);                // N
    int* cursor = cnt + N_;                                    // N (adjacent to cnt!)
    int* ptr = cursor + N_;                                    // N+4
    int* bsum = ptr + N_ + 4;                                  // 256

    const int nb_scan = (N_ + 255) / 256;
    const int POOL_BLOCKS = 2048;
    const int chunk = (N_ + POOL_BLOCKS - 1) / POOL_BLOCKS;
    const int gemm_blocks = (N_ + 63) / 64;

    // zero cnt+cursor, then fused setup: pack | bc | zero pools | hist | embed(8ch/thr)
    hipMemsetAsync(cnt, 0, (size_t)2 * N_ * sizeof(int), stream);
    const int nbH = (E_ + 255) / 256;
    const int nbA = (N_ * 16 + 255) / 256;
    k_setup<<<257 + 64 + nbH + nbA, 256, 0, stream>>>(
        ei, cnt, E_,
        x, embed_w, embed_b, h_bf,
        gat_lin_w, mha_v_w, mha_v_b, mha_o_w, mha_o_b,
        Bpack, bc, gsum, N_, nbH);

    // CSR scan + scatter
    k_scan_local<<<nb_scan, 256, 0, stream>>>(cnt, ptr, bsum, N_);
    k_scan_add2<<<nb_scan, 256, 0, stream>>>(ptr, bsum, N_, E_);
    k_scatter<<<(E_ + 255) / 256, 256, 0, stream>>>(ei, edge_attr, ptr, cursor, erec, E_);

    for (int i = 0; i < 3; ++i) {
        k_gemm_mfma<true, false><<<gemm_blocks, 256, 0, stream>>>(
            h_bf, Bpack + (size_t)i * 16384, nullptr, hl_bf, nullptr,
            gat_att_src + i * 128, gat_att_dst + i * 128, asrc, adst, N_);
        if (i < 2)
            k_node_agg<false><<<(N_ + 3) / 4, 256, 0, stream>>>(
                hl_bf, ptr, erec, asrc, adst,
                gat_edge_w + (size_t)i * 512, gat_att_edge + i * 128,
                gat_bias + i * 128, ln_g + i * 128, ln_b + i * 128, h_buf, h_bf, N_);
        else
            k_node_agg<true><<<(N_ + 3) / 4, 256, 0, stream>>>(
                hl_bf, ptr, erec, asrc, adst,
                gat_edge_w + (size_t)i * 512, gat_att_edge + i * 128,
                gat_bias + i * 128, ln_g + i * 128, ln_b + i * 128, h_buf, h_bf, N_);
    }

    k_pool_part<<<POOL_BLOCKS, 256, 0, stream>>>(h_bf, batch, gsum, gmax, N_, chunk);
    k_tail<<<G_ + gemm_blocks, 256, 0, stream>>>(
        gsum, gmax, batch, haddock,
        had_w1, had_b1, had_w2, had_b2,
        int_w1, int_b1, int_w2, int_b2, int_w3, int_b3,
        aff_w1, aff_b1, aff_w2, aff_b2, aff_w3, aff_b3,
        inter_out, aff_out,
        h_bf, Bpack + (size_t)3 * 16384, bc, attn_out, G_, N_, N_);
}

// Round 17
// 341.607 us; speedup vs baseline: 1.0051x; 1.0051x over previous
//
#include <hip/hip_runtime.h>
#include <hip/hip_bf16.h>

typedef float v4 __attribute__((ext_vector_type(4)));
typedef float f32x4 __attribute__((ext_vector_type(4)));
typedef short bf16x8 __attribute__((ext_vector_type(8)));
typedef unsigned short us8 __attribute__((ext_vector_type(8)));
typedef unsigned short us4 __attribute__((ext_vector_type(4)));

__device__ __forceinline__ unsigned short f2bf(float f) {
    unsigned u = __float_as_uint(f);
    u = (u + 0x7FFFu + ((u >> 16) & 1u)) >> 16;
    return (unsigned short)u;
}
__device__ __forceinline__ float bf2f(unsigned short s) {
    return __uint_as_float(((unsigned)s) << 16);
}

// ---------------- fused setup, partition order: [pack | bc | zero | hist | embed]
// embed: 8 channels/thread — x loaded once to regs, w read as float4 pairs.
// cnt+cursor must be zeroed by hipMemsetAsync BEFORE this kernel.
__global__ __launch_bounds__(256) void k_setup(
    const int* __restrict__ ei, int* __restrict__ cnt, int E_,
    const float* __restrict__ x, const float* __restrict__ embed_w,
    const float* __restrict__ embed_b, unsigned short* __restrict__ h_bf,
    const float* __restrict__ gat_lin_w,
    const float* __restrict__ vw, const float* __restrict__ vb,
    const float* __restrict__ ow, const float* __restrict__ ob,
    unsigned short* __restrict__ Bpack, float* __restrict__ bc,
    float* __restrict__ gzero,
    int n, int nbH) {
    int b = blockIdx.x, tid = threadIdx.x;
    if (b < 256) {
        // pack W[m] into MFMA B-fragment order; m==3 computes Wc = Vw@Ow on the fly
        int m = b >> 6;
        int idx = (b & 63) * 256 + tid;  // 0..16383
        int e = idx & 7, l = (idx >> 3) & 63, kb = (idx >> 9) & 3, c = idx >> 11;
        int k = kb * 32 + ((l >> 4) << 3) + e;
        int col = c * 16 + (l & 15);
        float val;
        if (m < 3) {
            val = gat_lin_w[(size_t)m * 16384 + k * 128 + col];
        } else {
            val = 0.f;
            for (int m2 = 0; m2 < 128; ++m2) val += vw[k * 128 + m2] * ow[m2 * 128 + col];
        }
        Bpack[(size_t)m * 16384 + idx] = f2bf(val);
    } else if (b == 256) {
        // bc = vb @ Ow + ob
        if (tid < 128) {
            float bv = ob[tid];
            for (int m2 = 0; m2 < 128; ++m2) bv += vb[m2] * ow[m2 * 128 + tid];
            bc[tid] = bv;
        }
    } else if (b < 257 + 64) {
        // zero gsum + gmax (2*G*128 floats = 16384)
        int idx = (b - 257) * 256 + tid;
        if (idx < 16384) gzero[idx] = 0.f;
    } else if (b < 257 + 64 + nbH) {
        // histogram of dst degrees (cnt pre-zeroed by memset)
        int e = (b - 257 - 64) * 256 + tid;
        if (e < E_) atomicAdd(&cnt[ei[E_ + e]], 1);
    } else {
        // embed: 8 channels/thread; h_bf = bf16(relu(x @ embed_w + embed_b))
        int idx = (b - 257 - 64 - nbH) * 256 + tid;  // over n*16
        if (idx >= n * 16) return;
        int node = idx >> 4;
        int j0 = (idx & 15) * 8;
        float xv[20];
#pragma unroll
        for (int k = 0; k < 20; ++k) xv[k] = x[node * 20 + k];
        v4 acc0 = *(const v4*)&embed_b[j0];
        v4 acc1 = *(const v4*)&embed_b[j0 + 4];
#pragma unroll
        for (int k = 0; k < 20; ++k) {
            v4 w0 = *(const v4*)&embed_w[k * 128 + j0];
            v4 w1 = *(const v4*)&embed_w[k * 128 + j0 + 4];
#pragma unroll
            for (int j = 0; j < 4; ++j) acc0[j] += xv[k] * w0[j];
#pragma unroll
            for (int j = 0; j < 4; ++j) acc1[j] += xv[k] * w1[j];
        }
        us8 o;
#pragma unroll
        for (int j = 0; j < 4; ++j) o[j] = f2bf(fmaxf(acc0[j], 0.f));
#pragma unroll
        for (int j = 0; j < 4; ++j) o[4 + j] = f2bf(fmaxf(acc1[j], 0.f));
        *(us8*)&h_bf[(size_t)node * 128 + j0] = o;
    }
}

// ---------------- CSR build (once; edge_index is layer-invariant) ----------------

__global__ __launch_bounds__(256) void k_scan_local(const int* __restrict__ cnt,
                                                    int* __restrict__ ptr,
                                                    int* __restrict__ bsum, int n) {
    __shared__ int s[256];
    int t = threadIdx.x, i = blockIdx.x * 256 + t;
    int v = (i < n) ? cnt[i] : 0;
    s[t] = v;
    __syncthreads();
    for (int o = 1; o < 256; o <<= 1) {
        int x = (t >= o) ? s[t - o] : 0;
        __syncthreads();
        s[t] += x;
        __syncthreads();
    }
    if (i < n) ptr[i] = s[t] - v;
    if (t == 255) bsum[blockIdx.x] = s[255];
}

// fused: each block computes its own exclusive bsum-prefix, then adds it.
__global__ __launch_bounds__(256) void k_scan_add2(int* __restrict__ ptr,
                                                   const int* __restrict__ bsum,
                                                   int n, int E_) {
    __shared__ int ws[4];
    __shared__ int soff;
    int t = threadIdx.x;
    int part = 0;
    for (int j = t; j < (int)blockIdx.x; j += 256) part += bsum[j];
#pragma unroll
    for (int o = 32; o; o >>= 1) part += __shfl_xor(part, o);
    if ((t & 63) == 0) ws[t >> 6] = part;
    __syncthreads();
    if (t == 0) soff = ws[0] + ws[1] + ws[2] + ws[3];
    __syncthreads();
    int i = blockIdx.x * 256 + t;
    if (i < n) ptr[i] += soff;
    if (i == 0) ptr[n] = E_;
}

// scatter into CSR slots; ea stored as bf16x4 (8B)
__global__ __launch_bounds__(256) void k_scatter(const int* __restrict__ ei,
                                                 const float* __restrict__ edge_attr,
                                                 const int* __restrict__ ptr,
                                                 int* __restrict__ cursor,
                                                 int* __restrict__ esrc_s,
                                                 unsigned short* __restrict__ ea_s, int E_) {
    int e = blockIdx.x * 256 + threadIdx.x;
    if (e >= E_) return;
    int d = ei[E_ + e];
    int p = ptr[d] + atomicAdd(&cursor[d], 1);
    esrc_s[p] = ei[e];
    v4 ea = ((const v4*)edge_attr)[e];
    us4 o;
#pragma unroll
    for (int j = 0; j < 4; ++j) o[j] = f2bf(ea[j]);
    *(us4*)&ea_s[(size_t)p * 4] = o;
}

// ---------------- MFMA GEMM [nn,128](bf16) x [128,128](packed bf16) ----------------
template <bool ALPHAS, bool OUTF32>
__global__ __launch_bounds__(256) void k_gemm_mfma(
    const unsigned short* __restrict__ A,     // [Npad][128] bf16
    const unsigned short* __restrict__ Bpack, // [32][64][8] bf16
    const float* __restrict__ bias,           // OUTF32
    unsigned short* __restrict__ out_bf,      // !OUTF32
    float* __restrict__ out_f32,              // OUTF32
    const float* __restrict__ avs, const float* __restrict__ avd,
    float* __restrict__ asrc, float* __restrict__ adst, int nn) {
    __shared__ float lds[64][132];
    int tid = threadIdx.x;
    int w = tid >> 6, l = tid & 63;
    int row0 = blockIdx.x * 64;
    int arow = row0 + w * 16 + (l & 15);
    int koff = (l >> 4) * 8;

    bf16x8 a[4];
#pragma unroll
    for (int kb = 0; kb < 4; ++kb)
        a[kb] = *(const bf16x8*)&A[(size_t)arow * 128 + kb * 32 + koff];

    const bf16x8* bp = (const bf16x8*)Bpack;
    f32x4 acc[8];
#pragma unroll
    for (int c = 0; c < 8; ++c) {
        f32x4 z = {0.f, 0.f, 0.f, 0.f};
        acc[c] = z;
#pragma unroll
        for (int kb = 0; kb < 4; ++kb)
            acc[c] = __builtin_amdgcn_mfma_f32_16x16x32_bf16(a[kb], bp[(c * 4 + kb) * 64 + l],
                                                             acc[c], 0, 0, 0);
    }

    int colb = l & 15;
    int rowb = w * 16 + (l >> 4) * 4;
#pragma unroll
    for (int c = 0; c < 8; ++c)
#pragma unroll
        for (int r = 0; r < 4; ++r)
            lds[rowb + r][c * 16 + colb] = acc[c][r];
    __syncthreads();

    int rl = tid >> 2, q = tid & 3;
    int gr = row0 + rl;
    if (gr >= nn) return;
    float v[32];
#pragma unroll
    for (int j = 0; j < 8; ++j)
        *(f32x4*)&v[j * 4] = *(const f32x4*)&lds[rl][q * 32 + j * 4];

    if (ALPHAS) {
        float ps = 0.f, pd = 0.f;
#pragma unroll
        for (int j = 0; j < 32; ++j) {
            ps += v[j] * avs[q * 32 + j];
            pd += v[j] * avd[q * 32 + j];
        }
        asrc[(size_t)gr * 4 + q] = ps;
        adst[(size_t)gr * 4 + q] = pd;
    }
    if (OUTF32) {
#pragma unroll
        for (int j = 0; j < 32; ++j) v[j] += bias[q * 32 + j];
#pragma unroll
        for (int j = 0; j < 8; ++j)
            *(f32x4*)&out_f32[(size_t)gr * 128 + q * 32 + j * 4] = *(f32x4*)&v[j * 4];
    } else {
        us8 o[4];
#pragma unroll
        for (int t = 0; t < 4; ++t)
#pragma unroll
            for (int j = 0; j < 8; ++j) o[t][j] = f2bf(v[t * 8 + j]);
#pragma unroll
        for (int t = 0; t < 4; ++t)
            *(us8*)&out_bf[(size_t)gr * 128 + q * 32 + t * 8] = o[t];
    }
}

// wave per node, 4 edge-groups x 16 lanes x 8 channels; bf16 gathers; 2-way unrolled
// edge loop. LAST: also writes f32 h (model output).
template <bool LAST>
__global__ __launch_bounds__(256) void k_node_agg(
    const unsigned short* __restrict__ hl_bf, const int* __restrict__ ptr,
    const int* __restrict__ esrc_s, const unsigned short* __restrict__ ea_s,
    const float* __restrict__ asrc, const float* __restrict__ adst,
    const float* __restrict__ edge_w, const float* __restrict__ a_edge,
    const float* __restrict__ bias, const float* __restrict__ lng,
    const float* __restrict__ lnb, float* __restrict__ h_f32,
    unsigned short* __restrict__ h_bf, int n) {
    __shared__ float aew[16];  // [k*4 + head]
    int tid = threadIdx.x;
    if (tid < 16) {
        int k = tid >> 2, hh = tid & 3;
        float s = 0.f;
        for (int c = 0; c < 32; ++c) s += edge_w[k * 128 + hh * 32 + c] * a_edge[hh * 32 + c];
        aew[tid] = s;
    }
    __syncthreads();

    int node = blockIdx.x * 4 + (tid >> 6);
    if (node >= n) return;
    int lane = tid & 63;
    int g = lane >> 4;        // edge group 0..3
    int l16 = lane & 15;
    int c0 = l16 * 8;         // 8 channels per lane
    int hh = l16 >> 2;        // head of these channels

    float aewc0 = aew[hh], aewc1 = aew[4 + hh], aewc2 = aew[8 + hh], aewc3 = aew[12 + hh];
    int start = ptr[node], end = ptr[node + 1];
    float adn = adst[(size_t)node * 4 + hh];
    us8 res_bf = *(const us8*)&h_bf[(size_t)node * 128 + c0];  // residual, early issue

    float acc[8] = {};
    float den = 0.f;
    int p = start + g;
    int s0 = (p < end) ? esrc_s[p] : 0;
    int s1 = (p + 4 < end) ? esrc_s[p + 4] : 0;
    for (; p < end; p += 8) {
        bool v1 = (p + 4 < end);
        int sn0 = (p + 8 < end) ? esrc_s[p + 8] : 0;
        int sn1 = (p + 12 < end) ? esrc_s[p + 12] : 0;
        us4 ea0 = *(const us4*)&ea_s[(size_t)p * 4];
        us4 ea1 = *(const us4*)&ea_s[(size_t)(v1 ? (p + 4) : p) * 4];
        us8 hv0 = *(const us8*)&hl_bf[(size_t)s0 * 128 + c0];
        us8 hv1 = *(const us8*)&hl_bf[(size_t)s1 * 128 + c0];
        float as0 = asrc[(size_t)s0 * 4 + hh];
        float as1 = asrc[(size_t)s1 * 4 + hh];
        float a0 = as0 + adn + bf2f(ea0[0]) * aewc0 + bf2f(ea0[1]) * aewc1 +
                   bf2f(ea0[2]) * aewc2 + bf2f(ea0[3]) * aewc3;
        float a1 = as1 + adn + bf2f(ea1[0]) * aewc0 + bf2f(ea1[1]) * aewc1 +
                   bf2f(ea1[2]) * aewc2 + bf2f(ea1[3]) * aewc3;
        a0 = a0 > 0.f ? a0 : 0.2f * a0;
        a1 = a1 > 0.f ? a1 : 0.2f * a1;
        float ex0 = __expf(a0);
        float ex1 = v1 ? __expf(a1) : 0.f;
        den += ex0 + ex1;
#pragma unroll
        for (int j = 0; j < 8; ++j)
            acc[j] += ex0 * bf2f(hv0[j]) + ex1 * bf2f(hv1[j]);
        s0 = sn0; s1 = sn1;
    }

    // combine the 4 edge groups (lanes l16, l16+16, l16+32, l16+48 share channels)
#pragma unroll
    for (int j = 0; j < 8; ++j) {
        acc[j] += __shfl_xor(acc[j], 16);
        acc[j] += __shfl_xor(acc[j], 32);
    }
    den += __shfl_xor(den, 16);
    den += __shfl_xor(den, 32);

    float inv = 1.f / (den + 1e-16f);
    v4 b0 = *(const v4*)&bias[c0];
    v4 b1 = *(const v4*)&bias[c0 + 4];
    float v[8];
#pragma unroll
    for (int j = 0; j < 4; ++j) v[j] = acc[j] * inv + b0[j] + bf2f(res_bf[j]);
#pragma unroll
    for (int j = 0; j < 4; ++j) v[4 + j] = acc[4 + j] * inv + b1[j] + bf2f(res_bf[4 + j]);

    float s = 0.f, sq = 0.f;
#pragma unroll
    for (int j = 0; j < 8; ++j) { s += v[j]; sq += v[j] * v[j]; }
#pragma unroll
    for (int o = 1; o < 16; o <<= 1) { s += __shfl_xor(s, o); sq += __shfl_xor(sq, o); }
    float mu = s * (1.f / 128.f);
    float var = sq * (1.f / 128.f) - mu * mu;
    float rs = rsqrtf(var + 1e-5f);

    if (g == 0) {
        v4 g0 = *(const v4*)&lng[c0];
        v4 g1 = *(const v4*)&lng[c0 + 4];
        v4 lb0 = *(const v4*)&lnb[c0];
        v4 lb1 = *(const v4*)&lnb[c0 + 4];
        v4 o0, o1;
#pragma unroll
        for (int j = 0; j < 4; ++j) o0[j] = fmaxf((v[j] - mu) * rs * g0[j] + lb0[j], 0.f);
#pragma unroll
        for (int j = 0; j < 4; ++j) o1[j] = fmaxf((v[4 + j] - mu) * rs * g1[j] + lb1[j], 0.f);
        us8 ob;
#pragma unroll
        for (int j = 0; j < 4; ++j) ob[j] = f2bf(o0[j]);
#pragma unroll
        for (int j = 0; j < 4; ++j) ob[4 + j] = f2bf(o1[j]);
        *(us8*)&h_bf[(size_t)node * 128 + c0] = ob;
        if (LAST) {
            *(v4*)&h_f32[(size_t)node * 128 + c0] = o0;
            *(v4*)&h_f32[(size_t)node * 128 + c0 + 4] = o1;
        }
    }
}

__device__ __forceinline__ int lower_bound_i(const int* a, int n, int key) {
    int lo = 0, hi = n;
    while (lo < hi) {
        int mid = (lo + hi) >> 1;
        if (a[mid] < key) lo = mid + 1; else hi = mid;
    }
    return lo;
}

// ---------------- two-stage pooling (bf16 input) ----------------

__global__ __launch_bounds__(256) void k_pool_part(const unsigned short* __restrict__ h_bf,
                                                   const int* __restrict__ batch,
                                                   float* __restrict__ gsum,
                                                   float* __restrict__ gmax,
                                                   int n, int chunk) {
    int start = blockIdx.x * chunk;
    int end = min(start + chunk, n);
    if (start >= end) return;
    int c0 = (threadIdx.x & 63) * 2;
    int strm = threadIdx.x >> 6;
    float s0 = 0.f, s1 = 0.f, m0 = 0.f, m1 = 0.f;
    int curg = -1;
    for (int node = start + strm; node < end; node += 4) {
        int g = batch[node];
        if (g != curg) {
            if (curg >= 0) {
                atomicAdd(&gsum[curg * 128 + c0], s0);
                atomicAdd(&gsum[curg * 128 + c0 + 1], s1);
                atomicMax((int*)&gmax[curg * 128 + c0], __float_as_int(m0));
                atomicMax((int*)&gmax[curg * 128 + c0 + 1], __float_as_int(m1));
            }
            curg = g; s0 = s1 = 0.f; m0 = m1 = 0.f;
        }
        unsigned u = *(const unsigned*)&h_bf[(size_t)node * 128 + c0];
        float v0 = __uint_as_float(u << 16);
        float v1 = __uint_as_float(u & 0xffff0000u);
        s0 += v0; s1 += v1;
        m0 = fmaxf(m0, v0); m1 = fmaxf(m1, v1);
    }
    if (curg >= 0) {
        atomicAdd(&gsum[curg * 128 + c0], s0);
        atomicAdd(&gsum[curg * 128 + c0 + 1], s1);
        atomicMax((int*)&gmax[curg * 128 + c0], __float_as_int(m0));
        atomicMax((int*)&gmax[curg * 128 + c0 + 1], __float_as_int(m1));
    }
}

// ---------------- fused tail: graph_out (blocks 0..G-1) | MHA GEMM (rest) ----------------
__global__ __launch_bounds__(256) void k_tail(
    const float* __restrict__ gsum, const float* __restrict__ gmax,
    const int* __restrict__ batch, const float* __restrict__ hf,
    const float* __restrict__ had_w1, const float* __restrict__ had_b1,
    const float* __restrict__ had_w2, const float* __restrict__ had_b2,
    const float* __restrict__ int_w1, const float* __restrict__ int_b1,
    const float* __restrict__ int_w2, const float* __restrict__ int_b2,
    const float* __restrict__ int_w3, const float* __restrict__ int_b3,
    const float* __restrict__ aff_w1, const float* __restrict__ aff_b1,
    const float* __restrict__ aff_w2, const float* __restrict__ aff_b2,
    const float* __restrict__ aff_w3, const float* __restrict__ aff_b3,
    float* __restrict__ inter_out, float* __restrict__ aff_out,
    const unsigned short* __restrict__ A, const unsigned short* __restrict__ Bpack,
    const float* __restrict__ bias, float* __restrict__ out_f32,
    int G_, int nn, int n) {
    __shared__ float lds[64][132];
    int tid = threadIdx.x;
    if ((int)blockIdx.x < G_) {
        // ---- graph_out ----
        __shared__ float comb[384];
        __shared__ float h1[128];
        __shared__ float z1[2][128];
        __shared__ float z2[2][64];
        int g = blockIdx.x;
        if (tid < 128) {
            int start = lower_bound_i(batch, n, g);
            int end = lower_bound_i(batch, n, g + 1);
            float cntf = (float)(end - start);
            comb[tid] = gsum[g * 128 + tid] / cntf;
            comb[128 + tid] = gmax[g * 128 + tid];
            float acc = had_b1[tid];
#pragma unroll
            for (int k = 0; k < 12; ++k) acc += hf[g * 12 + k] * had_w1[k * 128 + tid];
            h1[tid] = fmaxf(acc, 0.f);
        }
        __syncthreads();
        if (tid < 128) {
            float a2 = had_b2[tid];
            for (int k = 0; k < 128; ++k) a2 += h1[k] * had_w2[k * 128 + tid];
            comb[256 + tid] = a2;
        }
        __syncthreads();
        int hsel = tid >> 7, j = tid & 127;
        const float* w1 = hsel ? aff_w1 : int_w1;
        const float* b1 = hsel ? aff_b1 : int_b1;
        const float* w2 = hsel ? aff_w2 : int_w2;
        const float* b2 = hsel ? aff_b2 : int_b2;
        const float* w3 = hsel ? aff_w3 : int_w3;
        const float* b3 = hsel ? aff_b3 : int_b3;
        float acc = b1[j];
        for (int k = 0; k < 384; ++k) acc += comb[k] * w1[k * 128 + j];
        z1[hsel][j] = fmaxf(acc, 0.f);
        __syncthreads();
        if (j < 64) {
            float a2 = b2[j];
            for (int k = 0; k < 128; ++k) a2 += z1[hsel][k] * w2[k * 64 + j];
            z2[hsel][j] = fmaxf(a2, 0.f);
        }
        __syncthreads();
        if (j == 0) {
            float a3 = b3[0];
            for (int k = 0; k < 64; ++k) a3 += z2[hsel][k] * w3[k];
            if (hsel) aff_out[g] = a3;
            else inter_out[g] = 1.f / (1.f + __expf(-a3));
        }
        return;
    }
    // ---- MHA GEMM (OUTF32 path) ----
    int w = tid >> 6, l = tid & 63;
    int row0 = ((int)blockIdx.x - G_) * 64;
    int arow = row0 + w * 16 + (l & 15);
    int koff = (l >> 4) * 8;

    bf16x8 a[4];
#pragma unroll
    for (int kb = 0; kb < 4; ++kb)
        a[kb] = *(const bf16x8*)&A[(size_t)arow * 128 + kb * 32 + koff];

    const bf16x8* bp = (const bf16x8*)Bpack;
    f32x4 acc[8];
#pragma unroll
    for (int c = 0; c < 8; ++c) {
        f32x4 z = {0.f, 0.f, 0.f, 0.f};
        acc[c] = z;
#pragma unroll
        for (int kb = 0; kb < 4; ++kb)
            acc[c] = __builtin_amdgcn_mfma_f32_16x16x32_bf16(a[kb], bp[(c * 4 + kb) * 64 + l],
                                                             acc[c], 0, 0, 0);
    }
    int colb = l & 15;
    int rowb = w * 16 + (l >> 4) * 4;
#pragma unroll
    for (int c = 0; c < 8; ++c)
#pragma unroll
        for (int r = 0; r < 4; ++r)
            lds[rowb + r][c * 16 + colb] = acc[c][r];
    __syncthreads();

    int rl = tid >> 2, q = tid & 3;
    int gr = row0 + rl;
    if (gr >= nn) return;
    float v[32];
#pragma unroll
    for (int j = 0; j < 8; ++j)
        *(f32x4*)&v[j * 4] = *(const f32x4*)&lds[rl][q * 32 + j * 4];
#pragma unroll
    for (int j = 0; j < 32; ++j) v[j] += bias[q * 32 + j];
#pragma unroll
    for (int j = 0; j < 8; ++j)
        *(f32x4*)&out_f32[(size_t)gr * 128 + q * 32 + j * 4] = *(f32x4*)&v[j * 4];
}

extern "C" void kernel_launch(void* const* d_in, const int* in_sizes, int n_in,
                              void* d_out, int out_size, void* d_ws, size_t ws_size,
                              hipStream_t stream) {
    const float* x = (const float*)d_in[0];
    const float* edge_attr = (const float*)d_in[1];
    const float* haddock = (const float*)d_in[2];
    const int* ei = (const int*)d_in[3];
    const int* batch = (const int*)d_in[4];
    const float* embed_w = (const float*)d_in[5];
    const float* embed_b = (const float*)d_in[6];
    const float* gat_lin_w = (const float*)d_in[7];
    const float* gat_att_src = (const float*)d_in[8];
    const float* gat_att_dst = (const float*)d_in[9];
    const float* gat_edge_w = (const float*)d_in[10];
    const float* gat_att_edge = (const float*)d_in[11];
    const float* gat_bias = (const float*)d_in[12];
    const float* ln_g = (const float*)d_in[13];
    const float* ln_b = (const float*)d_in[14];
    const float* had_w1 = (const float*)d_in[15];
    const float* had_b1 = (const float*)d_in[16];
    const float* had_w2 = (const float*)d_in[17];
    const float* had_b2 = (const float*)d_in[18];
    const float* int_w1 = (const float*)d_in[19];
    const float* int_b1 = (const float*)d_in[20];
    const float* int_w2 = (const float*)d_in[21];
    const float* int_b2 = (const float*)d_in[22];
    const float* int_w3 = (const float*)d_in[23];
    const float* int_b3 = (const float*)d_in[24];
    const float* aff_w1 = (const float*)d_in[25];
    const float* aff_b1 = (const float*)d_in[26];
    const float* aff_w2 = (const float*)d_in[27];
    const float* aff_b2 = (const float*)d_in[28];
    const float* aff_w3 = (const float*)d_in[29];
    const float* aff_b3 = (const float*)d_in[30];
    const float* mha_v_w = (const float*)d_in[31];
    const float* mha_v_b = (const float*)d_in[32];
    const float* mha_o_w = (const float*)d_in[33];
    const float* mha_o_b = (const float*)d_in[34];

    const int N_ = in_sizes[0] / 20;
    const int E_ = in_sizes[1] / 4;
    const int G_ = in_sizes[2] / 12;
    const int Npad = (N_ + 63) & ~63;

    float* out_f = (float*)d_out;
    float* inter_out = out_f;
    float* aff_out = out_f + G_;
    float* attn_out = out_f + 2 * G_;
    float* h_buf = attn_out + (size_t)N_ * 128;  // f32 h output (written by last layer)

    // workspace layout (16B-aligned sections)
    unsigned short* h_bf = (unsigned short*)d_ws;              // Npad*128
    unsigned short* hl_bf = h_bf + (size_t)Npad * 128;         // Npad*128
    unsigned short* Bpack = hl_bf + (size_t)Npad * 128;        // 4*16384
    unsigned short* ea_s = Bpack + 4 * 16384;                  // E*4 (bf16)
    float* bc = (float*)(ea_s + (size_t)E_ * 4);               // 128
    float* asrc = bc + 128;                                    // N*4
    float* adst = asrc + (size_t)N_ * 4;                       // N*4
    float* gsum = adst + (size_t)N_ * 4;                       // G*128
    float* gmax = gsum + (size_t)G_ * 128;                     // G*128 (adjacent to gsum!)
    int* cnt = (int*)(gmax + (size_t)G_ * 128);                // N
    int* cursor = cnt + N_;                                    // N (adjacent to cnt!)
    int* ptr = cursor + N_;                                    // N+4
    int* bsum = ptr + N_ + 4;                                  // 256
    int* esrc_s = bsum + 256;                                  // E

    const int nb_scan = (N_ + 255) / 256;
    const int POOL_BLOCKS = 2048;
    const int chunk = (N_ + POOL_BLOCKS - 1) / POOL_BLOCKS;
    const int gemm_blocks = (N_ + 63) / 64;

    // zero cnt+cursor, then fused setup: pack | bc | zero pools | hist | embed(8ch/thr)
    hipMemsetAsync(cnt, 0, (size_t)2 * N_ * sizeof(int), stream);
    const int nbH = (E_ + 255) / 256;
    const int nbA = (N_ * 16 + 255) / 256;
    k_setup<<<257 + 64 + nbH + nbA, 256, 0, stream>>>(
        ei, cnt, E_,
        x, embed_w, embed_b, h_bf,
        gat_lin_w, mha_v_w, mha_v_b, mha_o_w, mha_o_b,
        Bpack, bc, gsum, N_, nbH);

    // CSR scan + scatter
    k_scan_local<<<nb_scan, 256, 0, stream>>>(cnt, ptr, bsum, N_);
    k_scan_add2<<<nb_scan, 256, 0, stream>>>(ptr, bsum, N_, E_);
    k_scatter<<<(E_ + 255) / 256, 256, 0, stream>>>(ei, edge_attr, ptr, cursor,
                                                    esrc_s, ea_s, E_);

    for (int i = 0; i < 3; ++i) {
        k_gemm_mfma<true, false><<<gemm_blocks, 256, 0, stream>>>(
            h_bf, Bpack + (size_t)i * 16384, nullptr, hl_bf, nullptr,
            gat_att_src + i * 128, gat_att_dst + i * 128, asrc, adst, N_);
        if (i < 2)
            k_node_agg<false><<<(N_ + 3) / 4, 256, 0, stream>>>(
                hl_bf, ptr, esrc_s, ea_s, asrc, adst,
                gat_edge_w + (size_t)i * 512, gat_att_edge + i * 128,
                gat_bias + i * 128, ln_g + i * 128, ln_b + i * 128, h_buf, h_bf, N_);
        else
            k_node_agg<true><<<(N_ + 3) / 4, 256, 0, stream>>>(
                hl_bf, ptr, esrc_s, ea_s, asrc, adst,
                gat_edge_w + (size_t)i * 512, gat_att_edge + i * 128,
                gat_bias + i * 128, ln_g + i * 128, ln_b + i * 128, h_buf, h_bf, N_);
    }

    k_pool_part<<<POOL_BLOCKS, 256, 0, stream>>>(h_bf, batch, gsum, gmax, N_, chunk);
    k_tail<<<G_ + gemm_blocks, 256, 0, stream>>>(
        gsum, gmax, batch, haddock,
        had_w1, had_b1, had_w2, had_b2,
        int_w1, int_b1, int_w2, int_b2, int_w3, int_b3,
        aff_w1, aff_b1, aff_w2, aff_b2, aff_w3, aff_b3,
        inter_out, aff_out,
        h_bf, Bpack + (size_t)3 * 16384, bc, attn_out, G_, N_, N_);
}